// Round 1
// baseline (402.845 us; speedup 1.0000x reference)
//
#include <hip/hip_runtime.h>
#include <math.h>

#define N_NODES 8192
#define F_IN 512
#define NH1 8
#define C1 8
#define D1 64   // NH1*C1
#define NC 16
#define E_EDGES 262144
#define TOT_EDGES (E_EDGES + N_NODES)
#define NEG_SLOPE 0.2f

// ---------------- GEMM1: h1pre[N,64] = x[N,512] @ W1[512,64] ----------------
__global__ __launch_bounds__(256) void gemm1_k(const float* __restrict__ x,
                                               const float* __restrict__ W1,
                                               float* __restrict__ h1pre) {
    __shared__ __align__(16) float As[32 * 68];  // [BK=32][BM=64 +4 pad]
    __shared__ __align__(16) float Bs[32 * 68];  // [BK=32][BN=64 +4 pad]
    int tid = threadIdx.x;
    int rowBase = blockIdx.x * 64;
    int rm = tid >> 4, rn = tid & 15;
    float acc[4][4] = {};
    for (int k0 = 0; k0 < F_IN; k0 += 32) {
#pragma unroll
        for (int j = 0; j < 8; ++j) {           // A tile: 64 rows x 32 k
            int i = tid + 256 * j;
            int r = i >> 5, c = i & 31;
            As[c * 68 + r] = x[(rowBase + r) * F_IN + k0 + c];
        }
#pragma unroll
        for (int j = 0; j < 8; ++j) {           // B tile: 32 k x 64 cols
            int i = tid + 256 * j;
            int rr = i >> 6, cc = i & 63;
            Bs[rr * 68 + cc] = W1[(k0 + rr) * D1 + cc];
        }
        __syncthreads();
#pragma unroll
        for (int kk = 0; kk < 32; ++kk) {
            float4 a = *(const float4*)&As[kk * 68 + rm * 4];
            float4 b = *(const float4*)&Bs[kk * 68 + rn * 4];
            float av[4] = {a.x, a.y, a.z, a.w};
            float bv[4] = {b.x, b.y, b.z, b.w};
#pragma unroll
            for (int jj = 0; jj < 4; ++jj)
#pragma unroll
                for (int ll = 0; ll < 4; ++ll)
                    acc[jj][ll] = fmaf(av[jj], bv[ll], acc[jj][ll]);
        }
        __syncthreads();
    }
#pragma unroll
    for (int jj = 0; jj < 4; ++jj) {
        float4 o = {acc[jj][0], acc[jj][1], acc[jj][2], acc[jj][3]};
        *(float4*)&h1pre[(size_t)(rowBase + rm * 4 + jj) * D1 + rn * 4] = o;
    }
}

// -------- logits1: als1/ald1[N,8] = per-head dot of h1pre with a_src/a_dst --------
__global__ void logits1_k(const float* __restrict__ h1pre,
                          const float* __restrict__ a_src1, const float* __restrict__ a_dst1,
                          float* __restrict__ als1, float* __restrict__ ald1) {
    int i = blockIdx.x * blockDim.x + threadIdx.x;  // n*8 + h
    if (i >= N_NODES * NH1) return;
    int h = i & 7;
    const float* hp = h1pre + (size_t)(i >> 3) * D1 + h * C1;
    float s = 0.f, d = 0.f;
#pragma unroll
    for (int c = 0; c < C1; ++c) {
        float v = hp[c];
        s = fmaf(v, a_src1[h * C1 + c], s);
        d = fmaf(v, a_dst1[h * C1 + c], d);
    }
    als1[i] = s;
    ald1[i] = d;
}

// ---------------- CSR build: histogram / scan / scatter ----------------
__global__ void hist_k(const int* __restrict__ ei, int* __restrict__ counts) {
    int i = blockIdx.x * blockDim.x + threadIdx.x;
    if (i >= TOT_EDGES) return;
    int dst = (i < E_EDGES) ? ei[E_EDGES + i] : (i - E_EDGES);
    atomicAdd(&counts[dst], 1);
}

__global__ __launch_bounds__(1024) void scan_k(const int* __restrict__ counts,
                                               int* __restrict__ offsets, int* __restrict__ cursor) {
    __shared__ int part[1024];
    int t = threadIdx.x;
    int local[8];
    int s = 0;
#pragma unroll
    for (int j = 0; j < 8; ++j) { local[j] = counts[t * 8 + j]; s += local[j]; }
    part[t] = s;
    __syncthreads();
    for (int d = 1; d < 1024; d <<= 1) {   // Hillis-Steele inclusive scan
        int v = (t >= d) ? part[t - d] : 0;
        __syncthreads();
        part[t] += v;
        __syncthreads();
    }
    int run = (t == 0) ? 0 : part[t - 1];
#pragma unroll
    for (int j = 0; j < 8; ++j) {
        offsets[t * 8 + j] = run;
        cursor[t * 8 + j] = run;
        run += local[j];
    }
    if (t == 1023) offsets[8192] = run;
}

__global__ void scatter_k(const int* __restrict__ ei, int* __restrict__ cursor, int* __restrict__ csr) {
    int i = blockIdx.x * blockDim.x + threadIdx.x;
    if (i >= TOT_EDGES) return;
    int src, dst;
    if (i < E_EDGES) { src = ei[i]; dst = ei[E_EDGES + i]; }
    else             { src = i - E_EDGES; dst = src; }
    int pos = atomicAdd(&cursor[dst], 1);
    csr[pos] = src;
}

// ---------------- Layer-1 softmax + aggregation, one wave per dst node ----------------
__global__ __launch_bounds__(64) void agg1_k(const float* __restrict__ h1pre,
                                             const float* __restrict__ als1, const float* __restrict__ ald1,
                                             const int* __restrict__ offsets, const int* __restrict__ csr,
                                             const float* __restrict__ b1, float* __restrict__ out1) {
    int n = blockIdx.x, t = threadIdx.x;
    int beg = offsets[n], end = offsets[n + 1];
    int h = t & 7;                      // phase 1/2: 8 lanes per head
    float aldh = ald1[n * NH1 + h];
    float m = -3.4e38f;
    for (int i = beg + (t >> 3); i < end; i += 8) {
        int s = csr[i];
        float v = als1[s * NH1 + h] + aldh;
        v = v > 0.f ? v : NEG_SLOPE * v;
        m = fmaxf(m, v);
    }
    m = fmaxf(m, __shfl_xor(m, 8));
    m = fmaxf(m, __shfl_xor(m, 16));
    m = fmaxf(m, __shfl_xor(m, 32));
    float den = 0.f;
    for (int i = beg + (t >> 3); i < end; i += 8) {
        int s = csr[i];
        float v = als1[s * NH1 + h] + aldh;
        v = v > 0.f ? v : NEG_SLOPE * v;
        den += expf(v - m);
    }
    den += __shfl_xor(den, 8);
    den += __shfl_xor(den, 16);
    den += __shfl_xor(den, 32);
    // phase 3: lane t owns output column t -> head q = t>>3
    int q = t >> 3;
    float mq = __shfl(m, q);     // lane q holds head q stats
    float dq = __shfl(den, q);
    float aldq = ald1[n * NH1 + q];
    float acc = 0.f;
    for (int i = beg; i < end; ++i) {
        int s = csr[i];
        float v = als1[s * NH1 + q] + aldq;
        v = v > 0.f ? v : NEG_SLOPE * v;
        float w = expf(v - mq);
        acc = fmaf(w, h1pre[(size_t)s * D1 + t], acc);
    }
    float val = acc / dq + b1[t];
    out1[(size_t)n * D1 + t] = val > 0.f ? val : expm1f(val);   // ELU
}

// ---------------- GEMM2: h2pre[N,16] = out1[N,64] @ W2[64,16] ----------------
__global__ __launch_bounds__(256) void gemm2_k(const float* __restrict__ out1,
                                               const float* __restrict__ W2,
                                               float* __restrict__ h2pre) {
    __shared__ float w2s[D1 * NC];  // 1024
    __shared__ float ot[16 * D1];   // 1024
    int tid = threadIdx.x;
    int nb = blockIdx.x * 16;
#pragma unroll
    for (int j = 0; j < 4; ++j) {
        w2s[tid + 256 * j] = W2[tid + 256 * j];
        ot[tid + 256 * j] = out1[(size_t)nb * D1 + tid + 256 * j];
    }
    __syncthreads();
    int nl = tid >> 4, c = tid & 15;
    float acc = 0.f;
#pragma unroll
    for (int k = 0; k < D1; ++k) acc = fmaf(ot[nl * D1 + k], w2s[k * NC + c], acc);
    h2pre[(size_t)(nb + nl) * NC + c] = acc;
}

__global__ void logits2_k(const float* __restrict__ h2pre,
                          const float* __restrict__ a_src2, const float* __restrict__ a_dst2,
                          float* __restrict__ als2, float* __restrict__ ald2) {
    int n = blockIdx.x * blockDim.x + threadIdx.x;
    if (n >= N_NODES) return;
    const float* hp = h2pre + (size_t)n * NC;
    float s = 0.f, d = 0.f;
#pragma unroll
    for (int c = 0; c < NC; ++c) {
        float v = hp[c];
        s = fmaf(v, a_src2[c], s);
        d = fmaf(v, a_dst2[c], d);
    }
    als2[n] = s;
    ald2[n] = d;
}

// ------- Layer-2 softmax + aggregation + bias + fused log_softmax, one wave/node -------
__global__ __launch_bounds__(64) void agg2_k(const float* __restrict__ h2pre,
                                             const float* __restrict__ als2, const float* __restrict__ ald2,
                                             const int* __restrict__ offsets, const int* __restrict__ csr,
                                             const float* __restrict__ b2,
                                             float* __restrict__ z, float* __restrict__ out_ls) {
    int n = blockIdx.x, t = threadIdx.x;
    int beg = offsets[n], end = offsets[n + 1];
    float aldn = ald2[n];
    float m = -3.4e38f;
    for (int i = beg + t; i < end; i += 64) {
        float v = als2[csr[i]] + aldn;
        v = v > 0.f ? v : NEG_SLOPE * v;
        m = fmaxf(m, v);
    }
#pragma unroll
    for (int d = 1; d < 64; d <<= 1) m = fmaxf(m, __shfl_xor(m, d));
    float den = 0.f;
    for (int i = beg + t; i < end; i += 64) {
        float v = als2[csr[i]] + aldn;
        v = v > 0.f ? v : NEG_SLOPE * v;
        den += expf(v - m);
    }
#pragma unroll
    for (int d = 1; d < 64; d <<= 1) den += __shfl_xor(den, d);
    int eg = t >> 4, c = t & 15;   // 4 edge-groups x 16 channels
    float acc = 0.f;
    for (int i = beg + eg; i < end; i += 4) {
        int s = csr[i];
        float v = als2[s] + aldn;
        v = v > 0.f ? v : NEG_SLOPE * v;
        acc = fmaf(expf(v - m), h2pre[(size_t)s * NC + c], acc);
    }
    acc += __shfl_xor(acc, 16);
    acc += __shfl_xor(acc, 32);    // all lanes now hold full sum for channel c
    float zv = acc / den + b2[c];
    if (t < 16) z[(size_t)n * NC + t] = zv;
    // log_softmax over the 16 channels (xor 1,2,4,8 stays within 16-lane groups)
    float zm = zv;
#pragma unroll
    for (int d = 1; d < 16; d <<= 1) zm = fmaxf(zm, __shfl_xor(zm, d));
    float se = expf(zv - zm);
#pragma unroll
    for (int d = 1; d < 16; d <<= 1) se += __shfl_xor(se, d);
    if (t < 16) out_ls[(size_t)n * NC + t] = zv - (zm + logf(se));
}

// ---------------- Gram: out[8192,8192] = z @ z^T ----------------
__global__ __launch_bounds__(256) void gram_k(const float* __restrict__ z,
                                              float* __restrict__ out) {
    __shared__ __align__(16) float rz[64 * 16];   // 64 row vectors
    int tid = threadIdx.x;
    int colBase = blockIdx.x * 256;
    int rowBase = blockIdx.y * 64;
    ((float4*)rz)[tid] = ((const float4*)z)[rowBase * 4 + tid];
    int j = colBase + tid;
    float c[16];
#pragma unroll
    for (int k4 = 0; k4 < 4; ++k4) {
        float4 v = ((const float4*)(z + (size_t)j * 16))[k4];
        c[k4 * 4 + 0] = v.x; c[k4 * 4 + 1] = v.y; c[k4 * 4 + 2] = v.z; c[k4 * 4 + 3] = v.w;
    }
    __syncthreads();
#pragma unroll 4
    for (int r = 0; r < 64; ++r) {
        const float* zr = &rz[r * 16];
        float acc = 0.f;
#pragma unroll
        for (int k = 0; k < 16; ++k) acc = fmaf(c[k], zr[k], acc);
        out[(size_t)(rowBase + r) * N_NODES + j] = acc;
    }
}

extern "C" void kernel_launch(void* const* d_in, const int* in_sizes, int n_in,
                              void* d_out, int out_size, void* d_ws, size_t ws_size,
                              hipStream_t stream) {
    (void)in_sizes; (void)n_in; (void)out_size; (void)ws_size;
    const float* x      = (const float*)d_in[0];
    const int*   ei     = (const int*)d_in[1];
    const float* W1     = (const float*)d_in[2];
    const float* a_src1 = (const float*)d_in[3];
    const float* a_dst1 = (const float*)d_in[4];
    const float* b1     = (const float*)d_in[5];
    const float* W2     = (const float*)d_in[6];
    const float* a_src2 = (const float*)d_in[7];
    const float* a_dst2 = (const float*)d_in[8];
    const float* b2     = (const float*)d_in[9];
    float* out = (float*)d_out;

    char* ws = (char*)d_ws;                    // all offsets 256B-aligned
    float* h1pre  = (float*)(ws + 0);          // 2 MB
    float* out1   = (float*)(ws + 2097152);    // 2 MB
    float* als1   = (float*)(ws + 4194304);    // 256 KB
    float* ald1   = (float*)(ws + 4456448);    // 256 KB
    float* h2pre  = (float*)(ws + 4718592);    // 512 KB
    float* als2   = (float*)(ws + 5242880);    // 32 KB
    float* ald2   = (float*)(ws + 5275648);    // 32 KB
    float* zarr   = (float*)(ws + 5308416);    // 512 KB
    int*   counts = (int*)  (ws + 5832704);    // 32 KB
    int*   offsets= (int*)  (ws + 5865472);    // 8193 ints
    int*   cursor = (int*)  (ws + 5898496);    // 32 KB
    int*   csr    = (int*)  (ws + 5931264);    // 1.03 MB

    hipMemsetAsync(counts, 0, N_NODES * sizeof(int), stream);
    hist_k<<<(TOT_EDGES + 255) / 256, 256, 0, stream>>>(ei, counts);
    scan_k<<<1, 1024, 0, stream>>>(counts, offsets, cursor);
    scatter_k<<<(TOT_EDGES + 255) / 256, 256, 0, stream>>>(ei, cursor, csr);

    gemm1_k<<<N_NODES / 64, 256, 0, stream>>>(x, W1, h1pre);
    logits1_k<<<(N_NODES * NH1 + 255) / 256, 256, 0, stream>>>(h1pre, a_src1, a_dst1, als1, ald1);
    agg1_k<<<N_NODES, 64, 0, stream>>>(h1pre, als1, ald1, offsets, csr, b1, out1);

    gemm2_k<<<N_NODES / 16, 256, 0, stream>>>(out1, W2, h2pre);
    logits2_k<<<N_NODES / 256, 256, 0, stream>>>(h2pre, a_src2, a_dst2, als2, ald2);
    agg2_k<<<N_NODES, 64, 0, stream>>>(h2pre, als2, ald2, offsets, csr, b2, zarr, out);

    gram_k<<<dim3(N_NODES / 256, N_NODES / 64), 256, 0, stream>>>(zarr, out + (size_t)N_NODES * NC);
}